// Round 16
// baseline (402.529 us; speedup 1.0000x reference)
//
#include <hip/hip_runtime.h>
#include <hip/hip_bf16.h>
#include <math.h>

// Problem constants
#define BATCH 16
#define NTOK 1024      // 32*32
#define HID 256
#define KMEM 4
#define DIN 272
#define DINP 288       // DIN zero-padded to /32
#define DFF 1024
#define LN_EPS 1e-5f

using short8 = __attribute__((ext_vector_type(8))) short;
using short4v = __attribute__((ext_vector_type(4))) short;
using floatx4 = __attribute__((ext_vector_type(4))) float;

__device__ inline short f2bf(float f) {
  unsigned u = __builtin_bit_cast(unsigned, f);
  u += 0x7fff + ((u >> 16) & 1);  // RNE
  return (short)(u >> 16);
}
__device__ inline float bf2f(short s) {
  unsigned u = ((unsigned)(unsigned short)s) << 16;
  return __builtin_bit_cast(float, u);
}

#define QSCALE 0.0625f  // 1/sqrt(256)

// ---------------------------------------------------------------------------
// pos embed: pos[t][j] = j<128 ? col_embed[t%32][j] : row_embed[t/32][j-128]
// ---------------------------------------------------------------------------
__global__ __launch_bounds__(256) void pos_kernel(
    const float* __restrict__ row_e, const float* __restrict__ col_e,
    float* __restrict__ pos) {
  int t = blockIdx.x;
  int j = threadIdx.x;
  float v = (j < 128) ? col_e[(t & 31) * 128 + j]
                      : row_e[(t >> 5) * 128 + (j - 128)];
  pos[t * 256 + j] = v;
}

// ---------------------------------------------------------------------------
// All weight transposes+cvt in ONE dispatch.  W[K][N] fp32 -> Wt[N][Kd] bf16.
// ---------------------------------------------------------------------------
struct WtJob {
  const float* src;
  short* dst;
  int K, Kd, N, ntx, start;
};
struct WtJobs {
  WtJob j[9];
};

__global__ __launch_bounds__(256) void wt_cvt_all_kernel(WtJobs jobs) {
  __shared__ short tile[32][33];
  int bid = blockIdx.x;
  int ji = 0;
#pragma unroll
  for (int i = 1; i < 9; ++i)
    if (bid >= jobs.j[i].start) ji = i;
  const float* W = jobs.j[ji].src;
  short* Wt = jobs.j[ji].dst;
  int K = jobs.j[ji].K, Kd = jobs.j[ji].Kd, N = jobs.j[ji].N;
  int local = bid - jobs.j[ji].start;
  int n0 = (local % jobs.j[ji].ntx) * 32;
  int k0 = (local / jobs.j[ji].ntx) * 32;
  int tx = threadIdx.x & 31, ty8 = threadIdx.x >> 5;
#pragma unroll
  for (int i = 0; i < 4; i++) {
    int k = k0 + ty8 + i * 8;
    int n = n0 + tx;
    float v = (k < K && n < N) ? W[(long)k * N + n] : 0.f;
    tile[ty8 + i * 8][tx] = f2bf(v);
  }
  __syncthreads();
#pragma unroll
  for (int i = 0; i < 4; i++) {
    int n = n0 + ty8 + i * 8;
    int k = k0 + tx;
    if (n < N && k < Kd) Wt[(long)n * Kd + k] = tile[tx][ty8 + i * 8];
  }
}

// ---------------------------------------------------------------------------
// kv projection, single-pass 64x256 tile (N=256 in one block, A read ONCE).
// A fp32 channel-major [4*16][272][1024], transpose+cvt fused into staging
// (conflict-free); Wt bf16 [256][288] double-buffered in LDS.
// 4 waves, each 64 rows x 64 cols = 4x4 frags.  Grid = 65536/64 = 1024.
// Epilogue: ktp[r][c] = bf16(val+pos) direct; ktv = V^T via LDS transpose.
// ---------------------------------------------------------------------------
__global__ __launch_bounds__(256) void kvproj_kernel(
    const float* __restrict__ mf, const short* __restrict__ Wt,
    const float* __restrict__ bias, short* __restrict__ ktp,
    short* __restrict__ ktv, const float* __restrict__ pos) {
  __shared__ short As[2][64][40];
  __shared__ short Bs[2][256][40];  // reused as Ts[64][260] in epilogue
  int nwg = gridDim.x;
  int bid = blockIdx.x;
  int h = (bid & 7) * (nwg >> 3) + (bid >> 3);  // XCD chunk swizzle
  int row0 = h * 64;
  int slice = row0 >> 10, tok0 = row0 & 1023;
  int tid = threadIdx.x;
  int w = tid >> 6, lane = tid & 63;
  int lcol = lane & 15, kg = lane >> 4;
  int wcol = w * 64;

  const float* Abf = mf + (long)slice * DIN * NTOK + tok0;
  int atok = tid & 63, acb = (tid >> 6) * 8;
  int brow = tid >> 2, bk = (tid & 3) * 8;

  float rf[8];
  short8 rb[4];
  // prologue: k-tile 0 -> buf 0
#pragma unroll
  for (int j = 0; j < 8; ++j)
    rf[j] = (acb + j < DIN) ? Abf[(long)(acb + j) * NTOK + atok] : 0.f;
  {
    short8 s;
#pragma unroll
    for (int j = 0; j < 8; ++j) s[j] = f2bf(rf[j]);
    *reinterpret_cast<short8*>(&As[0][atok][acb]) = s;
  }
#pragma unroll
  for (int i = 0; i < 4; ++i) {
    rb[i] = *reinterpret_cast<const short8*>(
        &Wt[(long)(brow + i * 64) * DINP + bk]);
    *reinterpret_cast<short8*>(&Bs[0][brow + i * 64][bk]) = rb[i];
  }
  __syncthreads();

  floatx4 acc[4][4];
#pragma unroll
  for (int m = 0; m < 4; ++m)
#pragma unroll
    for (int n = 0; n < 4; ++n) acc[m][n] = (floatx4){0.f, 0.f, 0.f, 0.f};

  const int NT = DINP >> 5;  // 9
  for (int t = 0; t < NT; ++t) {
    int cur = t & 1;
    if (t + 1 < NT) {
      int ko = (t + 1) << 5;
#pragma unroll
      for (int j = 0; j < 8; ++j)
        rf[j] = (ko + acb + j < DIN) ? Abf[(long)(ko + acb + j) * NTOK + atok]
                                     : 0.f;
#pragma unroll
      for (int i = 0; i < 4; ++i)
        rb[i] = *reinterpret_cast<const short8*>(
            &Wt[(long)(brow + i * 64) * DINP + ko + bk]);
    }
    short8 af[4], bf[4];
#pragma unroll
    for (int m = 0; m < 4; ++m)
      af[m] = *reinterpret_cast<const short8*>(
          &As[cur][m * 16 + lcol][kg * 8]);
#pragma unroll
    for (int n = 0; n < 4; ++n)
      bf[n] = *reinterpret_cast<const short8*>(
          &Bs[cur][wcol + n * 16 + lcol][kg * 8]);
#pragma unroll
    for (int m = 0; m < 4; ++m)
#pragma unroll
      for (int n = 0; n < 4; ++n)
        acc[m][n] = __builtin_amdgcn_mfma_f32_16x16x32_bf16(af[m], bf[n],
                                                            acc[m][n], 0, 0, 0);
    if (t + 1 < NT) {
      int nxt = cur ^ 1;
      short8 s;
#pragma unroll
      for (int j = 0; j < 8; ++j) s[j] = f2bf(rf[j]);
      *reinterpret_cast<short8*>(&As[nxt][atok][acb]) = s;
#pragma unroll
      for (int i = 0; i < 4; ++i)
        *reinterpret_cast<short8*>(&Bs[nxt][brow + i * 64][bk]) = rb[i];
    }
    __syncthreads();
  }

  // epilogue: ktp direct; ktv via LDS transpose (Ts aliases Bs, stride 260)
  short* Ts = &Bs[0][0][0];  // [64][260] = 33280 shorts <= 40960
#pragma unroll
  for (int n = 0; n < 4; ++n) {
    int cl = wcol + n * 16 + lcol;  // 0..255
    float bv = bias[cl];
#pragma unroll
    for (int m = 0; m < 4; ++m) {
      int rl = m * 16 + kg * 4;
#pragma unroll
      for (int q = 0; q < 4; ++q) {
        float val = acc[m][n][q] + bv;
        Ts[(rl + q) * 260 + cl] = f2bf(val);
        ktp[(long)(row0 + rl + q) * 256 + cl] =
            f2bf(val + pos[(tok0 + rl + q) * 256 + cl]);
      }
    }
  }
  __syncthreads();
  int t8 = tid & 7;
#pragma unroll
  for (int p = 0; p < 8; ++p) {
    int cl = p * 32 + (tid >> 3);
    short8 v;
#pragma unroll
    for (int j = 0; j < 8; ++j) v[j] = Ts[(t8 * 8 + j) * 260 + cl];
    *reinterpret_cast<short8*>(&ktv[(long)slice * (256 * 1024) +
                                    (long)cl * 1024 + tok0 + t8 * 8]) = v;
  }
}

// ---------------------------------------------------------------------------
// Unified MFMA bf16 GEMM with 2-phase prefetch pipeline.
// AFP32=false: A bf16 [M][K] row-major.
// AFP32=true:  A fp32 channel-major; transpose+cvt fused (conflict-free).
// Wt bf16 [N][K].  Tile 64x128, BK=32, 4 waves.
// OUTMODE 1: Cs bf16 relu.
// OUTMODE 3: q projection: Cs = x16 = bf16(val); q16p = bf16((val+pos)*QSCALE)
// OUTMODE 4: out projection: write recon[b][c][t] (transposed) + per-token
//            squared-error partials vs qf (pred_part[cx][row]).
// ---------------------------------------------------------------------------
template <int OUTMODE, bool AFP32>
__global__ __launch_bounds__(256) void gemm2_kernel(
    const void* __restrict__ Ap, const short* __restrict__ Wt,
    const float* __restrict__ bias, float* __restrict__ Cf,
    short* __restrict__ Cs, int M, int N, int K, int gxn,
    short* __restrict__ q16p, const float* __restrict__ pos,
    const float* __restrict__ qfp, float* __restrict__ ppart) {
  __shared__ short As[2][64][40];
  __shared__ short Bs[2][128][40];
  __shared__ float part_s[64][2];
  int nwg = gridDim.x;
  int cpx = nwg >> 3;
  int bid = blockIdx.x;
  int h = (bid & 7) * cpx + (bid >> 3);
  int cx = h % gxn;
  int ry = h / gxn;
  int row0 = ry * 64, col0 = cx * 128;
  int tid = threadIdx.x;
  int w = tid >> 6, lane = tid & 63;
  int wrow = (w >> 1) * 32, wcol = (w & 1) * 64;
  int lcol = lane & 15, kg = lane >> 4;

  const short* Ab16 = nullptr;
  const float* Abf = nullptr;
  int arow = tid >> 2, ak = (tid & 3) * 8;
  int atok = tid & 63, acb = (tid >> 6) * 8;
  if (AFP32) {
    int slice = row0 >> 10, tok0 = row0 & 1023;
    Abf = (const float*)Ap + (long)slice * DIN * NTOK + tok0;
  } else {
    Ab16 = (const short*)Ap + (long)row0 * K;
  }
  int brow = tid >> 2, bk = (tid & 3) * 8;
  const short* Bb = Wt + (long)col0 * K;
  bool bv0 = (col0 + brow) < N;
  bool bv1 = (col0 + brow + 64) < N;

  const short8 z8 = (short8){0, 0, 0, 0, 0, 0, 0, 0};
  short8 ra;
  float rf[8];
  short8 rb0, rb1;
  if (AFP32) {
#pragma unroll
    for (int j = 0; j < 8; ++j)
      rf[j] = (acb + j < DIN) ? Abf[(long)(acb + j) * NTOK + atok] : 0.f;
    short8 s;
#pragma unroll
    for (int j = 0; j < 8; ++j) s[j] = f2bf(rf[j]);
    *reinterpret_cast<short8*>(&As[0][atok][acb]) = s;
  } else {
    ra = *reinterpret_cast<const short8*>(&Ab16[(long)arow * K + ak]);
    *reinterpret_cast<short8*>(&As[0][arow][ak]) = ra;
  }
  rb0 = bv0 ? *reinterpret_cast<const short8*>(&Bb[(long)brow * K + bk]) : z8;
  rb1 = bv1 ? *reinterpret_cast<const short8*>(&Bb[(long)(brow + 64) * K + bk])
            : z8;
  *reinterpret_cast<short8*>(&Bs[0][brow][bk]) = rb0;
  *reinterpret_cast<short8*>(&Bs[0][brow + 64][bk]) = rb1;
  __syncthreads();

  floatx4 acc[2][4];
#pragma unroll
  for (int m = 0; m < 2; ++m)
#pragma unroll
    for (int n = 0; n < 4; ++n) acc[m][n] = (floatx4){0.f, 0.f, 0.f, 0.f};

  int NT = K >> 5;
  for (int t = 0; t < NT; ++t) {
    int cur = t & 1;
    if (t + 1 < NT) {
      int ko = (t + 1) << 5;
      if (AFP32) {
#pragma unroll
        for (int j = 0; j < 8; ++j)
          rf[j] = (ko + acb + j < DIN)
                      ? Abf[(long)(ko + acb + j) * NTOK + atok]
                      : 0.f;
      } else {
        ra = *reinterpret_cast<const short8*>(&Ab16[(long)arow * K + ko + ak]);
      }
      rb0 = bv0 ? *reinterpret_cast<const short8*>(&Bb[(long)brow * K + ko + bk])
                : z8;
      rb1 = bv1 ? *reinterpret_cast<const short8*>(
                      &Bb[(long)(brow + 64) * K + ko + bk])
                : z8;
    }
    short8 af[2], bf[4];
#pragma unroll
    for (int m = 0; m < 2; ++m)
      af[m] = *reinterpret_cast<const short8*>(
          &As[cur][wrow + m * 16 + lcol][kg * 8]);
#pragma unroll
    for (int n = 0; n < 4; ++n)
      bf[n] = *reinterpret_cast<const short8*>(
          &Bs[cur][wcol + n * 16 + lcol][kg * 8]);
#pragma unroll
    for (int m = 0; m < 2; ++m)
#pragma unroll
      for (int n = 0; n < 4; ++n)
        acc[m][n] = __builtin_amdgcn_mfma_f32_16x16x32_bf16(af[m], bf[n],
                                                            acc[m][n], 0, 0, 0);
    if (t + 1 < NT) {
      int nxt = cur ^ 1;
      if (AFP32) {
        short8 s;
#pragma unroll
        for (int j = 0; j < 8; ++j) s[j] = f2bf(rf[j]);
        *reinterpret_cast<short8*>(&As[nxt][atok][acb]) = s;
      } else {
        *reinterpret_cast<short8*>(&As[nxt][arow][ak]) = ra;
      }
      *reinterpret_cast<short8*>(&Bs[nxt][brow][bk]) = rb0;
      *reinterpret_cast<short8*>(&Bs[nxt][brow + 64][bk]) = rb1;
    }
    __syncthreads();
  }

  if (OUTMODE == 4) {
    int bb = row0 >> 10;
    int tb0 = (row0 & 1023) + wrow;
    float sqp[2][4] = {};
#pragma unroll
    for (int n = 0; n < 4; ++n) {
      int c = col0 + wcol + n * 16 + lcol;
      if (c < N) {
        float bv = bias[c];
#pragma unroll
        for (int m = 0; m < 2; ++m) {
          int tb = tb0 + m * 16 + kg * 4;
          long addr = ((long)bb * DIN + c) * 1024 + tb;
          float4 qv = *reinterpret_cast<const float4*>(&qfp[addr]);
          float4 ov;
          float v0 = acc[m][n][0] + bv;
          float v1 = acc[m][n][1] + bv;
          float v2 = acc[m][n][2] + bv;
          float v3 = acc[m][n][3] + bv;
          ov.x = v0;
          ov.y = v1;
          ov.z = v2;
          ov.w = v3;
          float d0 = v0 - qv.x, d1 = v1 - qv.y, d2 = v2 - qv.z, d3 = v3 - qv.w;
          sqp[m][0] = fmaf(d0, d0, sqp[m][0]);
          sqp[m][1] = fmaf(d1, d1, sqp[m][1]);
          sqp[m][2] = fmaf(d2, d2, sqp[m][2]);
          sqp[m][3] = fmaf(d3, d3, sqp[m][3]);
          *reinterpret_cast<float4*>(&Cf[addr]) = ov;
        }
      }
    }
#pragma unroll
    for (int m = 0; m < 2; ++m)
#pragma unroll
      for (int q = 0; q < 4; ++q) {
        float s = sqp[m][q];
        s += __shfl_xor(s, 1);
        s += __shfl_xor(s, 2);
        s += __shfl_xor(s, 4);
        s += __shfl_xor(s, 8);
        if (lcol == 0) part_s[wrow + m * 16 + kg * 4 + q][w & 1] = s;
      }
    __syncthreads();
    if (tid < 64)
      ppart[(long)cx * 16384 + row0 + tid] = part_s[tid][0] + part_s[tid][1];
    return;
  }

#pragma unroll
  for (int n = 0; n < 4; ++n) {
    int c = col0 + wcol + n * 16 + lcol;
    if (c >= N) continue;
    float bv = bias[c];
#pragma unroll
    for (int m = 0; m < 2; ++m) {
      int rbase = row0 + wrow + m * 16 + kg * 4;
      if (OUTMODE == 1) {
#pragma unroll
        for (int q = 0; q < 4; ++q)
          Cs[(long)(rbase + q) * N + c] = f2bf(fmaxf(acc[m][n][q] + bv, 0.f));
      } else if (OUTMODE == 3) {
#pragma unroll
        for (int q = 0; q < 4; ++q) {
          float val = acc[m][n][q] + bv;
          Cs[(long)(rbase + q) * N + c] = f2bf(val);
          q16p[(long)(rbase + q) * N + c] =
              f2bf((val + pos[((rbase + q) & 1023) * 256 + c]) * QSCALE);
        }
      }
    }
  }
}

// ---------------------------------------------------------------------------
// MFMA GEMM + fused residual(bf16) + LayerNorm epilogue.
// A bf16 [M][K] @ Wt bf16 [256][K] + bias + res16(bf16) -> LN -> x16out
// (in-place-safe vs res16: all res reads precede the stats barrier which
// precedes all writes; blocks own disjoint rows).  [EQ] also q16out.
// Tile 32x256 (full row), BK=32, 4 waves, 2-phase pipeline.  Grid = M/32.
// ---------------------------------------------------------------------------
template <bool EQ>
__global__ __launch_bounds__(256) void gemm_ln_kernel(
    const short* __restrict__ A, const short* __restrict__ Wt,
    const float* __restrict__ bias, const short* __restrict__ res16,
    const float* __restrict__ g, const float* __restrict__ bta,
    short* __restrict__ x16out, const float* __restrict__ pos,
    short* __restrict__ q16out, int K) {
  __shared__ short As[2][32][40];
  __shared__ short Bs[2][256][40];
  __shared__ float st_s[32][4];
  __shared__ float st_s2[32][4];
  int tid = threadIdx.x;
  int row0 = blockIdx.x * 32;
  int w = tid >> 6, lane = tid & 63, lcol = lane & 15, kg = lane >> 4;
  int arow = tid >> 2, ak = (tid & 3) * 8;  // tid<128 stages A
  int brow = tid >> 2, bk = (tid & 3) * 8;  // rows brow + i*64
  const short* Ab = A + (long)row0 * K;

  short8 ra, rb[4];
  if (tid < 128) ra = *reinterpret_cast<const short8*>(&Ab[(long)arow * K + ak]);
#pragma unroll
  for (int i = 0; i < 4; ++i)
    rb[i] = *reinterpret_cast<const short8*>(&Wt[(long)(brow + i * 64) * K + bk]);
  if (tid < 128) *reinterpret_cast<short8*>(&As[0][arow][ak]) = ra;
#pragma unroll
  for (int i = 0; i < 4; ++i)
    *reinterpret_cast<short8*>(&Bs[0][brow + i * 64][bk]) = rb[i];
  __syncthreads();

  floatx4 acc[2][4];
#pragma unroll
  for (int m = 0; m < 2; ++m)
#pragma unroll
    for (int n = 0; n < 4; ++n) acc[m][n] = (floatx4){0.f, 0.f, 0.f, 0.f};

  int NT = K >> 5;
  for (int t = 0; t < NT; ++t) {
    int cur = t & 1;
    if (t + 1 < NT) {
      int ko = (t + 1) << 5;
      if (tid < 128)
        ra = *reinterpret_cast<const short8*>(&Ab[(long)arow * K + ko + ak]);
#pragma unroll
      for (int i = 0; i < 4; ++i)
        rb[i] = *reinterpret_cast<const short8*>(
            &Wt[(long)(brow + i * 64) * K + ko + bk]);
    }
    short8 af[2], bf[4];
#pragma unroll
    for (int m = 0; m < 2; ++m)
      af[m] =
          *reinterpret_cast<const short8*>(&As[cur][m * 16 + lcol][kg * 8]);
#pragma unroll
    for (int n = 0; n < 4; ++n)
      bf[n] = *reinterpret_cast<const short8*>(
          &Bs[cur][w * 64 + n * 16 + lcol][kg * 8]);
#pragma unroll
    for (int m = 0; m < 2; ++m)
#pragma unroll
      for (int n = 0; n < 4; ++n)
        acc[m][n] = __builtin_amdgcn_mfma_f32_16x16x32_bf16(af[m], bf[n],
                                                            acc[m][n], 0, 0, 0);
    if (t + 1 < NT) {
      int nxt = cur ^ 1;
      if (tid < 128) *reinterpret_cast<short8*>(&As[nxt][arow][ak]) = ra;
#pragma unroll
      for (int i = 0; i < 4; ++i)
        *reinterpret_cast<short8*>(&Bs[nxt][brow + i * 64][bk]) = rb[i];
    }
    __syncthreads();
  }

  // epilogue: val = acc + bias + residual(bf16), LN over the 256-wide row
  float val[2][4][4];
#pragma unroll
  for (int n = 0; n < 4; ++n) {
    int c = w * 64 + n * 16 + lcol;
    float bv = bias[c];
#pragma unroll
    for (int m = 0; m < 2; ++m) {
      int rbase = row0 + m * 16 + kg * 4;
#pragma unroll
      for (int q = 0; q < 4; ++q)
        val[m][n][q] =
            acc[m][n][q] + bv + bf2f(res16[(long)(rbase + q) * 256 + c]);
    }
  }
  float s[2][4], s2[2][4];
#pragma unroll
  for (int m = 0; m < 2; ++m)
#pragma unroll
    for (int q = 0; q < 4; ++q) {
      float ss = 0.f, ss2 = 0.f;
#pragma unroll
      for (int n = 0; n < 4; ++n) {
        float v = val[m][n][q];
        ss += v;
        ss2 = fmaf(v, v, ss2);
      }
      ss += __shfl_xor(ss, 1);
      ss2 += __shfl_xor(ss2, 1);
      ss += __shfl_xor(ss, 2);
      ss2 += __shfl_xor(ss2, 2);
      ss += __shfl_xor(ss, 4);
      ss2 += __shfl_xor(ss2, 4);
      ss += __shfl_xor(ss, 8);
      ss2 += __shfl_xor(ss2, 8);
      s[m][q] = ss;
      s2[m][q] = ss2;
    }
  if (lcol == 0) {
#pragma unroll
    for (int m = 0; m < 2; ++m)
#pragma unroll
      for (int q = 0; q < 4; ++q) {
        st_s[m * 16 + kg * 4 + q][w] = s[m][q];
        st_s2[m * 16 + kg * 4 + q][w] = s2[m][q];
      }
  }
  __syncthreads();
#pragma unroll
  for (int m = 0; m < 2; ++m)
#pragma unroll
    for (int q = 0; q < 4; ++q) {
      int row = m * 16 + kg * 4 + q;
      float4 a4 = *reinterpret_cast<const float4*>(&st_s[row][0]);
      float4 b4 = *reinterpret_cast<const float4*>(&st_s2[row][0]);
      float S = (a4.x + a4.y) + (a4.z + a4.w);
      float S2 = (b4.x + b4.y) + (b4.z + b4.w);
      float mean = S * (1.f / 256.f);
      float var = S2 * (1.f / 256.f) - mean * mean;
      float inv = rsqrtf(var + LN_EPS);
#pragma unroll
      for (int n = 0; n < 4; ++n) {
        int c = w * 64 + n * 16 + lcol;
        float o = (val[m][n][q] - mean) * inv * g[c] + bta[c];
        long addr = (long)(row0 + row) * 256 + c;
        x16out[addr] = f2bf(o);
        if (EQ)
          q16out[addr] =
              f2bf((o + pos[((row0 + row) & 1023) * 256 + c]) * QSCALE);
      }
    }
}

// ---------------------------------------------------------------------------
// MFMA windowed attention. One block per (b,k,r) (grid 2048, XCD-swizzled).
// Q staged from global q16 (pos+scale pre-folded) via pure bf16 copy; Q/P
// alias one LDS buffer.  S = Q@K'^T (ktp direct); cross-wave softmax; P in
// LDS; O = P@V (ktv = V^T direct).  O bf16.
// ---------------------------------------------------------------------------
__global__ __launch_bounds__(256) void attn_kernel(
    const short* __restrict__ q16, const short* __restrict__ ktp,
    const short* __restrict__ ktv, short* __restrict__ o) {
  __shared__ short QP_s[32][264];
  __shared__ float st_mx[32][4];
  __shared__ float st_sm[32][4];
  int h = blockIdx.x;
  int xcd = h & 7, jj = h >> 3;
  int sidx = xcd * 8 + (jj >> 5);
  int r = jj & 31;
  int b = sidx & 15, k = sidx >> 4;
  int tid = threadIdx.x;
  int w = tid >> 6, lane = tid & 63, lcol = lane & 15, kg = lane >> 4;

  int r0 = max(r - 3, 0), r1 = min(r + 3, 31);
  int nkr = r1 - r0 + 1, nm = nkr * 32;
  const short* qb = q16 + ((long)b * NTOK + r * 32) * HID;
  const short* ktpb = ktp + ((long)(k * BATCH + b)) * NTOK * HID;
  const short* ktvb = ktv + ((long)(k * BATCH + b)) * NTOK * HID;

#pragma unroll
  for (int p = 0; p < 4; ++p) {
    int chunk = p * 256 + tid;
    int row = chunk >> 5, c8 = (chunk & 31) * 8;
    short8 v = *reinterpret_cast<const short8*>(&qb[(long)row * HID + c8]);
    *reinterpret_cast<short8*>(&QP_s[row][c8]) = v;
  }
  __syncthreads();

  floatx4 acc[2][4];
#pragma unroll
  for (int m = 0; m < 2; ++m)
#pragma unroll
    for (int n = 0; n < 4; ++n) acc[m][n] = (floatx4){0.f, 0.f, 0.f, 0.f};

  int tokn[4];
#pragma unroll
  for (int n = 0; n < 4; ++n) {
    int nf = w * 4 + n;
    int krow = min(r0 + (nf >> 1), 31);
    tokn[n] = krow * 32 + ((nf & 1) << 4) + lcol;
  }
#pragma unroll
  for (int s = 0; s < 8; ++s) {
    short8 af0 = *reinterpret_cast<const short8*>(&QP_s[lcol][s * 32 + kg * 8]);
    short8 af1 =
        *reinterpret_cast<const short8*>(&QP_s[16 + lcol][s * 32 + kg * 8]);
#pragma unroll
    for (int n = 0; n < 4; ++n) {
      short8 bfr = *reinterpret_cast<const short8*>(
          &ktpb[(long)tokn[n] * HID + s * 32 + kg * 8]);
      acc[0][n] =
          __builtin_amdgcn_mfma_f32_16x16x32_bf16(af0, bfr, acc[0][n], 0, 0, 0);
      acc[1][n] =
          __builtin_amdgcn_mfma_f32_16x16x32_bf16(af1, bfr, acc[1][n], 0, 0, 0);
    }
  }

  const float NEG = -3.0e38f;
  float mx[2][4];
#pragma unroll
  for (int m = 0; m < 2; ++m)
#pragma unroll
    for (int q = 0; q < 4; ++q) {
      int rr = m * 16 + kg * 4 + q;
      float vmax = NEG;
#pragma unroll
      for (int n = 0; n < 4; ++n) {
        int col = (w * 4 + n) * 16 + lcol;
        int ck = col & 31;
        bool ok = (col < nm) && (ck - rr <= 3) && (rr - ck <= 3);
        float v = ok ? acc[m][n][q] : NEG;
        acc[m][n][q] = v;
        vmax = fmaxf(vmax, v);
      }
      vmax = fmaxf(vmax, __shfl_xor(vmax, 1));
      vmax = fmaxf(vmax, __shfl_xor(vmax, 2));
      vmax = fmaxf(vmax, __shfl_xor(vmax, 4));
      vmax = fmaxf(vmax, __shfl_xor(vmax, 8));
      mx[m][q] = vmax;
    }
  if (lcol == 0) {
#pragma unroll
    for (int m = 0; m < 2; ++m)
#pragma unroll
      for (int q = 0; q < 4; ++q) st_mx[m * 16 + kg * 4 + q][w] = mx[m][q];
  }
  __syncthreads();
  float sm[2][4];
#pragma unroll
  for (int m = 0; m < 2; ++m)
#pragma unroll
    for (int q = 0; q < 4; ++q) {
      int rr = m * 16 + kg * 4 + q;
      float4 v4 = *reinterpret_cast<const float4*>(&st_mx[rr][0]);
      float g = fmaxf(fmaxf(v4.x, v4.y), fmaxf(v4.z, v4.w));
      float ss = 0.f;
#pragma unroll
      for (int n = 0; n < 4; ++n) {
        float v = acc[m][n][q];
        float pv = (v > -1.0e30f) ? exp2f((v - g) * 1.4426950408889634f) : 0.f;
        acc[m][n][q] = pv;
        ss += pv;
      }
      ss += __shfl_xor(ss, 1);
      ss += __shfl_xor(ss, 2);
      ss += __shfl_xor(ss, 4);
      ss += __shfl_xor(ss, 8);
      sm[m][q] = ss;
    }
  if (lcol == 0) {
#pragma unroll
    for (int m = 0; m < 2; ++m)
#pragma unroll
      for (int q = 0; q < 4; ++q) st_sm[m * 16 + kg * 4 + q][w] = sm[m][q];
  }
  __syncthreads();
#pragma unroll
  for (int m = 0; m < 2; ++m)
#pragma unroll
    for (int q = 0; q < 4; ++q) {
      int rr = m * 16 + kg * 4 + q;
      float4 v4 = *reinterpret_cast<const float4*>(&st_sm[rr][0]);
      float rinv = 1.0f / (v4.x + v4.y + v4.z + v4.w);
#pragma unroll
      for (int n = 0; n < 4; ++n) {
        QP_s[rr][(w * 4 + n) * 16 + lcol] = f2bf(acc[m][n][q] * rinv);
      }
    }
  __syncthreads();

  floatx4 oacc[2][4];
#pragma unroll
  for (int m = 0; m < 2; ++m)
#pragma unroll
    for (int n = 0; n < 4; ++n) oacc[m][n] = (floatx4){0.f, 0.f, 0.f, 0.f};

  for (int kb = 0; kb < nkr; ++kb) {
    short8 ap0 = *reinterpret_cast<const short8*>(&QP_s[lcol][kb * 32 + kg * 8]);
    short8 ap1 =
        *reinterpret_cast<const short8*>(&QP_s[16 + lcol][kb * 32 + kg * 8]);
    int tokb = (r0 + kb) * 32;
#pragma unroll
    for (int n = 0; n < 4; ++n) {
      int ch = w * 64 + n * 16 + lcol;
      short8 bv = *reinterpret_cast<const short8*>(
          &ktvb[(long)ch * NTOK + tokb + kg * 8]);
      oacc[0][n] =
          __builtin_amdgcn_mfma_f32_16x16x32_bf16(ap0, bv, oacc[0][n], 0, 0, 0);
      oacc[1][n] =
          __builtin_amdgcn_mfma_f32_16x16x32_bf16(ap1, bv, oacc[1][n], 0, 0, 0);
    }
  }
#pragma unroll
  for (int m = 0; m < 2; ++m)
#pragma unroll
    for (int n = 0; n < 4; ++n) {
      int ch = w * 64 + n * 16 + lcol;
#pragma unroll
      for (int q = 0; q < 4; ++q) {
        int rr = m * 16 + kg * 4 + q;
        o[((long)b * NTOK + r * 32 + rr) * (KMEM * HID) + k * HID + ch] =
            f2bf(oacc[m][n][q]);
      }
    }
}

// ---------------------------------------------------------------------------
// sum the 3 pred partials -> pred_sq, and global min/max of sqrt(pred_sq)
// ---------------------------------------------------------------------------
__global__ __launch_bounds__(256) void minmax_kernel(
    const float* __restrict__ ppart, float* __restrict__ pred_sq,
    float* __restrict__ mnmx) {
  int tid = threadIdx.x;
  float mn = INFINITY, mx = -INFINITY;
  for (int i = tid; i < BATCH * NTOK; i += 256) {
    float v = ppart[i] + ppart[16384 + i] + ppart[32768 + i];
    pred_sq[i] = v;
    float sv = sqrtf(v);
    mn = fminf(mn, sv);
    mx = fmaxf(mx, sv);
  }
#pragma unroll
  for (int off = 32; off > 0; off >>= 1) {
    mn = fminf(mn, __shfl_xor(mn, off));
    mx = fmaxf(mx, __shfl_xor(mx, off));
  }
  __shared__ float smn[4], smx[4];
  int wave = tid >> 6, lane = tid & 63;
  if (lane == 0) {
    smn[wave] = mn;
    smx[wave] = mx;
  }
  __syncthreads();
  if (tid == 0) {
    mn = fminf(fminf(smn[0], smn[1]), fminf(smn[2], smn[3]));
    mx = fmaxf(fmaxf(smx[0], smx[1]), fmaxf(smx[2], smx[3]));
    mnmx[0] = mn;
    mnmx[1] = mx;
  }
}

__global__ __launch_bounds__(256) void resize_kernel(
    const float* __restrict__ pred_sq, const float* __restrict__ mnmx,
    float* __restrict__ out) {
  long idx = (long)blockIdx.x * 256 + threadIdx.x;
  if (idx >= (long)BATCH * 256 * 256) return;
  int b = (int)(idx >> 16);
  int oy = (int)((idx >> 8) & 255), ox = (int)(idx & 255);
  float mn = mnmx[0], mx = mnmx[1];
  float inv = 1.0f / (mx - mn);
  float ys = oy * (31.0f / 255.0f);
  int y0 = (int)floorf(ys);
  int y1 = min(y0 + 1, 31);
  float fy = ys - (float)y0;
  float xs = ox * (31.0f / 255.0f);
  int x0 = (int)floorf(xs);
  int x1 = min(x0 + 1, 31);
  float fx = xs - (float)x0;
  const float* p = pred_sq + b * NTOK;
  float v00 = sqrtf(p[y0 * 32 + x0]), v01 = sqrtf(p[y0 * 32 + x1]);
  float v10 = sqrtf(p[y1 * 32 + x0]), v11 = sqrtf(p[y1 * 32 + x1]);
  float cA = v00 * (1.f - fy) + v10 * fy;
  float cB = v01 * (1.f - fy) + v11 * fy;
  float v = cA * (1.f - fx) + cB * fx;
  out[idx] = (v - mn) * inv;
}

// ---------------------------------------------------------------------------
extern "C" void kernel_launch(void* const* d_in, const int* in_sizes, int n_in,
                              void* d_out, int out_size, void* d_ws,
                              size_t ws_size, hipStream_t stream) {
  const float* qf = (const float*)d_in[0];
  const float* mf = (const float*)d_in[1];
  const float* qW = (const float*)d_in[2];
  const float* qb = (const float*)d_in[3];
  const float* kvW = (const float*)d_in[4];
  const float* kvb = (const float*)d_in[5];
  const float* row_e = (const float*)d_in[6];
  const float* col_e = (const float*)d_in[7];
  const float* aggW = (const float*)d_in[8];
  const float* aggb = (const float*)d_in[9];
  const float* n1g = (const float*)d_in[10];
  const float* n1b = (const float*)d_in[11];
  const float* l1W = (const float*)d_in[12];
  const float* l1b = (const float*)d_in[13];
  const float* l2W = (const float*)d_in[14];
  const float* l2b = (const float*)d_in[15];
  const float* n2g = (const float*)d_in[16];
  const float* n2b = (const float*)d_in[17];
  const float* outW = (const float*)d_in[18];
  const float* outb = (const float*)d_in[19];

  float* out = (float*)d_out;
  float* recon = out;                            // 16*272*1024
  float* pred = out + (long)BATCH * DIN * NTOK;  // 16*256*256

  // workspace layout (fp32 x dropped: residual carried in bf16 x16)
  float* ws = (float*)d_ws;
  float* pos = ws;                              // 262144 f   (1MB)
  short* x16 = (short*)(pos + 262144);          // 4194304 s  (8MB)
  short* q16 = x16 + 4194304;                   // 4194304 s  (8MB)
  short* ktp = q16 + 4194304;                   // 16777216 s (32MB)
  short* ktv = ktp + 16777216;                  // 16777216 s (32MB)
  short* buf16 = ktv + 16777216;                // 16777216 s (32MB)
  short* wt = buf16 + 16777216;
  short* wt_agg0 = wt;                  // [256][1024]
  short* wt_agg1 = wt_agg0 + 262144;    // [256][1024]
  short* wt_l1_0 = wt_agg1 + 262144;    // [1024][256]
  short* wt_l1_1 = wt_l1_0 + 262144;    // [1024][256]
  short* wt_l2_0 = wt_l1_1 + 262144;    // [256][1024]
  short* wt_l2_1 = wt_l2_0 + 262144;    // [256][1024]
  short* wt_out = wt_l2_1 + 262144;     // [272][256]
  short* wt_q = wt_out + 69632;         // [256][288]
  short* wt_kv = wt_q + 73728;          // [256][288]
  float* pred_part = (float*)(wt_kv + 73728);   // 49152 f (3 x 16384)
  float* pred_sq = pred_part + 49152;           // 16384 f
  float* mnmx = pred_sq + 16384;                // 2 f

  pos_kernel<<<NTOK, 256, 0, stream>>>(row_e, col_e, pos);

  // all weight transposes in one dispatch
  {
    WtJobs jobs;
    jobs.j[0] = {aggW, wt_agg0, 1024, 1024, 256, 8, 0};
    jobs.j[1] = {aggW + 262144, wt_agg1, 1024, 1024, 256, 8, 256};
    jobs.j[2] = {l1W, wt_l1_0, 256, 256, 1024, 32, 512};
    jobs.j[3] = {l1W + 262144, wt_l1_1, 256, 256, 1024, 32, 768};
    jobs.j[4] = {l2W, wt_l2_0, 1024, 1024, 256, 8, 1024};
    jobs.j[5] = {l2W + 262144, wt_l2_1, 1024, 1024, 256, 8, 1280};
    jobs.j[6] = {outW, wt_out, 256, 256, 272, 9, 1536};
    jobs.j[7] = {qW, wt_q, 272, 288, 256, 8, 1608};
    jobs.j[8] = {kvW, wt_kv, 272, 288, 256, 8, 1680};
    wt_cvt_all_kernel<<<1752, 256, 0, stream>>>(jobs);
  }

  // q projection: x16 (bf16 residual) + q16 = bf16((val+pos)*scale)
  gemm2_kernel<3, true><<<512, 256, 0, stream>>>(
      qf, wt_q, qb, nullptr, x16, BATCH * NTOK, HID, DINP, 2, q16, pos,
      nullptr, nullptr);
  // kv projection: single-pass 64x256 tile, mf read once
  kvproj_kernel<<<1024, 256, 0, stream>>>(mf, wt_kv, kvb, ktp, ktv, pos);

  for (int l = 0; l < 2; l++) {
    attn_kernel<<<2048, 256, 0, stream>>>(q16, ktp, ktv, buf16);
    // agg + LN1 fused (res = x16, in-place): -> x16
    gemm_ln_kernel<false><<<512, 256, 0, stream>>>(
        buf16, l ? wt_agg1 : wt_agg0, aggb + l * 256, x16, n1g + l * 256,
        n1b + l * 256, x16, nullptr, nullptr, KMEM * HID);
    // ff1: x16 @ wt_l1 -> relu bf16 buf16
    gemm2_kernel<1, false><<<2048, 256, 0, stream>>>(
        x16, l ? wt_l1_1 : wt_l1_0, l1b + l * 1024, nullptr, buf16,
        BATCH * NTOK, DFF, HID, 8, nullptr, nullptr, nullptr, nullptr);
    // ff2 + LN2 fused: l=0 also emits q16 for the next attn
    if (l == 0) {
      gemm_ln_kernel<true><<<512, 256, 0, stream>>>(
          buf16, wt_l2_0, l2b, x16, n2g, n2b, x16, pos, q16, DFF);
    } else {
      gemm_ln_kernel<false><<<512, 256, 0, stream>>>(
          buf16, wt_l2_1, l2b + 256, x16, n2g + 256, n2b + 256, x16, nullptr,
          nullptr, DFF);
    }
  }

  // out projection fused: x16 @ wt_out -> recon (transposed) + pred partials
  gemm2_kernel<4, false><<<768, 256, 0, stream>>>(
      x16, wt_out, outb, recon, nullptr, BATCH * NTOK, DIN, HID, 3, nullptr,
      nullptr, qf, pred_part);
  minmax_kernel<<<1, 256, 0, stream>>>(pred_part, pred_sq, mnmx);
  resize_kernel<<<(BATCH * 256 * 256) / 256, 256, 0, stream>>>(pred_sq, mnmx,
                                                               pred);
}

// Round 17
// 385.893 us; speedup vs baseline: 1.0431x; 1.0431x over previous
//
#include <hip/hip_runtime.h>
#include <hip/hip_bf16.h>
#include <math.h>

// Problem constants
#define BATCH 16
#define NTOK 1024      // 32*32
#define HID 256
#define KMEM 4
#define DIN 272
#define DINP 288       // DIN zero-padded to /32
#define DFF 1024
#define LN_EPS 1e-5f

using short8 = __attribute__((ext_vector_type(8))) short;
using short4v = __attribute__((ext_vector_type(4))) short;
using floatx4 = __attribute__((ext_vector_type(4))) float;

__device__ inline short f2bf(float f) {
  unsigned u = __builtin_bit_cast(unsigned, f);
  u += 0x7fff + ((u >> 16) & 1);  // RNE
  return (short)(u >> 16);
}
__device__ inline float bf2f(short s) {
  unsigned u = ((unsigned)(unsigned short)s) << 16;
  return __builtin_bit_cast(float, u);
}

#define QSCALE 0.0625f  // 1/sqrt(256)

// ---------------------------------------------------------------------------
// pos embed: pos[t][j] = j<128 ? col_embed[t%32][j] : row_embed[t/32][j-128]
// ---------------------------------------------------------------------------
__global__ __launch_bounds__(256) void pos_kernel(
    const float* __restrict__ row_e, const float* __restrict__ col_e,
    float* __restrict__ pos) {
  int t = blockIdx.x;
  int j = threadIdx.x;
  float v = (j < 128) ? col_e[(t & 31) * 128 + j]
                      : row_e[(t >> 5) * 128 + (j - 128)];
  pos[t * 256 + j] = v;
}

// ---------------------------------------------------------------------------
// All weight transposes+cvt in ONE dispatch.  W[K][N] fp32 -> Wt[N][Kd] bf16.
// ---------------------------------------------------------------------------
struct WtJob {
  const float* src;
  short* dst;
  int K, Kd, N, ntx, start;
};
struct WtJobs {
  WtJob j[9];
};

__global__ __launch_bounds__(256) void wt_cvt_all_kernel(WtJobs jobs) {
  __shared__ short tile[32][33];
  int bid = blockIdx.x;
  int ji = 0;
#pragma unroll
  for (int i = 1; i < 9; ++i)
    if (bid >= jobs.j[i].start) ji = i;
  const float* W = jobs.j[ji].src;
  short* Wt = jobs.j[ji].dst;
  int K = jobs.j[ji].K, Kd = jobs.j[ji].Kd, N = jobs.j[ji].N;
  int local = bid - jobs.j[ji].start;
  int n0 = (local % jobs.j[ji].ntx) * 32;
  int k0 = (local / jobs.j[ji].ntx) * 32;
  int tx = threadIdx.x & 31, ty8 = threadIdx.x >> 5;
#pragma unroll
  for (int i = 0; i < 4; i++) {
    int k = k0 + ty8 + i * 8;
    int n = n0 + tx;
    float v = (k < K && n < N) ? W[(long)k * N + n] : 0.f;
    tile[ty8 + i * 8][tx] = f2bf(v);
  }
  __syncthreads();
#pragma unroll
  for (int i = 0; i < 4; i++) {
    int n = n0 + ty8 + i * 8;
    int k = k0 + tx;
    if (n < N && k < Kd) Wt[(long)n * Kd + k] = tile[tx][ty8 + i * 8];
  }
}

// ---------------------------------------------------------------------------
// kv projection, two-pass 64x128 tile (grid 2048, gxn=2), 30 KB LDS.
// A fp32 channel-major, transpose+cvt fused into staging (conflict-free);
// 4 waves 2x2, wave 32x64.  Epilogue: ktp direct; ktv = V^T via LDS
// transpose (Ts aliases Bs) + coalesced short8 stores.
// ---------------------------------------------------------------------------
__global__ __launch_bounds__(256) void kvproj_kernel(
    const float* __restrict__ mf, const short* __restrict__ Wt,
    const float* __restrict__ bias, short* __restrict__ ktp,
    short* __restrict__ ktv, const float* __restrict__ pos) {
  __shared__ short As[2][64][40];
  __shared__ short Bs[2][128][40];  // reused as Ts[64][132] in epilogue
  int nwg = gridDim.x;
  int bid = blockIdx.x;
  int h = (bid & 7) * (nwg >> 3) + (bid >> 3);  // XCD chunk swizzle
  int cx = h & 1;
  int ry = h >> 1;
  int row0 = ry * 64, col0 = cx * 128;
  int slice = row0 >> 10, tok0 = row0 & 1023;
  int tid = threadIdx.x;
  int w = tid >> 6, lane = tid & 63;
  int wrow = (w >> 1) * 32, wcol = (w & 1) * 64;
  int lcol = lane & 15, kg = lane >> 4;

  const float* Abf = mf + (long)slice * DIN * NTOK + tok0;
  int atok = tid & 63, acb = (tid >> 6) * 8;
  int brow = tid >> 2, bk = (tid & 3) * 8;
  const short* Bb = Wt + (long)col0 * DINP;

  float rf[8];
  short8 rb0, rb1;
  // prologue: k-tile 0 -> buf 0
#pragma unroll
  for (int j = 0; j < 8; ++j)
    rf[j] = (acb + j < DIN) ? Abf[(long)(acb + j) * NTOK + atok] : 0.f;
  {
    short8 s;
#pragma unroll
    for (int j = 0; j < 8; ++j) s[j] = f2bf(rf[j]);
    *reinterpret_cast<short8*>(&As[0][atok][acb]) = s;
  }
  rb0 = *reinterpret_cast<const short8*>(&Bb[(long)brow * DINP + bk]);
  rb1 = *reinterpret_cast<const short8*>(&Bb[(long)(brow + 64) * DINP + bk]);
  *reinterpret_cast<short8*>(&Bs[0][brow][bk]) = rb0;
  *reinterpret_cast<short8*>(&Bs[0][brow + 64][bk]) = rb1;
  __syncthreads();

  floatx4 acc[2][4];
#pragma unroll
  for (int m = 0; m < 2; ++m)
#pragma unroll
    for (int n = 0; n < 4; ++n) acc[m][n] = (floatx4){0.f, 0.f, 0.f, 0.f};

  const int NT = DINP >> 5;  // 9
  for (int t = 0; t < NT; ++t) {
    int cur = t & 1;
    if (t + 1 < NT) {
      int ko = (t + 1) << 5;
#pragma unroll
      for (int j = 0; j < 8; ++j)
        rf[j] = (ko + acb + j < DIN) ? Abf[(long)(ko + acb + j) * NTOK + atok]
                                     : 0.f;
      rb0 = *reinterpret_cast<const short8*>(&Bb[(long)brow * DINP + ko + bk]);
      rb1 = *reinterpret_cast<const short8*>(
          &Bb[(long)(brow + 64) * DINP + ko + bk]);
    }
    short8 af[2], bf[4];
#pragma unroll
    for (int m = 0; m < 2; ++m)
      af[m] = *reinterpret_cast<const short8*>(
          &As[cur][wrow + m * 16 + lcol][kg * 8]);
#pragma unroll
    for (int n = 0; n < 4; ++n)
      bf[n] = *reinterpret_cast<const short8*>(
          &Bs[cur][wcol + n * 16 + lcol][kg * 8]);
#pragma unroll
    for (int m = 0; m < 2; ++m)
#pragma unroll
      for (int n = 0; n < 4; ++n)
        acc[m][n] = __builtin_amdgcn_mfma_f32_16x16x32_bf16(af[m], bf[n],
                                                            acc[m][n], 0, 0, 0);
    if (t + 1 < NT) {
      int nxt = cur ^ 1;
      short8 s;
#pragma unroll
      for (int j = 0; j < 8; ++j) s[j] = f2bf(rf[j]);
      *reinterpret_cast<short8*>(&As[nxt][atok][acb]) = s;
      *reinterpret_cast<short8*>(&Bs[nxt][brow][bk]) = rb0;
      *reinterpret_cast<short8*>(&Bs[nxt][brow + 64][bk]) = rb1;
    }
    __syncthreads();
  }

  // epilogue: ktp direct; ktv via LDS transpose (Ts aliases Bs, stride 132)
  short* Ts = &Bs[0][0][0];  // [64][132]
#pragma unroll
  for (int n = 0; n < 4; ++n) {
    int cl = wcol + n * 16 + lcol;  // 0..127
    int c = col0 + cl;
    float bv = bias[c];
#pragma unroll
    for (int m = 0; m < 2; ++m) {
      int rl = wrow + m * 16 + kg * 4;
#pragma unroll
      for (int q = 0; q < 4; ++q) {
        float val = acc[m][n][q] + bv;
        Ts[(rl + q) * 132 + cl] = f2bf(val);
        ktp[(long)(row0 + rl + q) * 256 + c] =
            f2bf(val + pos[(tok0 + rl + q) * 256 + c]);
      }
    }
  }
  __syncthreads();
  int t8 = tid & 7;
#pragma unroll
  for (int p = 0; p < 4; ++p) {
    int cl = p * 32 + (tid >> 3);
    short8 v;
#pragma unroll
    for (int j = 0; j < 8; ++j) v[j] = Ts[(t8 * 8 + j) * 132 + cl];
    *reinterpret_cast<short8*>(&ktv[(long)slice * (256 * 1024) +
                                    (long)(col0 + cl) * 1024 + tok0 +
                                    t8 * 8]) = v;
  }
}

// ---------------------------------------------------------------------------
// Unified MFMA bf16 GEMM with 2-phase prefetch pipeline.
// AFP32=false: A bf16 [M][K] row-major.
// AFP32=true:  A fp32 channel-major; transpose+cvt fused (conflict-free).
// Wt bf16 [N][K].  Tile 64x128, BK=32, 4 waves.
// OUTMODE 1: Cs bf16 relu.
// OUTMODE 3: q projection: Cs = x16 = bf16(val); q16p = bf16((val+pos)*QSCALE)
// OUTMODE 4: out projection: write recon[b][c][t] (transposed) + per-token
//            squared-error partials vs qf (pred_part[cx][row]).
// ---------------------------------------------------------------------------
template <int OUTMODE, bool AFP32>
__global__ __launch_bounds__(256) void gemm2_kernel(
    const void* __restrict__ Ap, const short* __restrict__ Wt,
    const float* __restrict__ bias, float* __restrict__ Cf,
    short* __restrict__ Cs, int M, int N, int K, int gxn,
    short* __restrict__ q16p, const float* __restrict__ pos,
    const float* __restrict__ qfp, float* __restrict__ ppart) {
  __shared__ short As[2][64][40];
  __shared__ short Bs[2][128][40];
  __shared__ float part_s[64][2];
  int nwg = gridDim.x;
  int cpx = nwg >> 3;
  int bid = blockIdx.x;
  int h = (bid & 7) * cpx + (bid >> 3);
  int cx = h % gxn;
  int ry = h / gxn;
  int row0 = ry * 64, col0 = cx * 128;
  int tid = threadIdx.x;
  int w = tid >> 6, lane = tid & 63;
  int wrow = (w >> 1) * 32, wcol = (w & 1) * 64;
  int lcol = lane & 15, kg = lane >> 4;

  const short* Ab16 = nullptr;
  const float* Abf = nullptr;
  int arow = tid >> 2, ak = (tid & 3) * 8;
  int atok = tid & 63, acb = (tid >> 6) * 8;
  if (AFP32) {
    int slice = row0 >> 10, tok0 = row0 & 1023;
    Abf = (const float*)Ap + (long)slice * DIN * NTOK + tok0;
  } else {
    Ab16 = (const short*)Ap + (long)row0 * K;
  }
  int brow = tid >> 2, bk = (tid & 3) * 8;
  const short* Bb = Wt + (long)col0 * K;
  bool bv0 = (col0 + brow) < N;
  bool bv1 = (col0 + brow + 64) < N;

  const short8 z8 = (short8){0, 0, 0, 0, 0, 0, 0, 0};
  short8 ra;
  float rf[8];
  short8 rb0, rb1;
  if (AFP32) {
#pragma unroll
    for (int j = 0; j < 8; ++j)
      rf[j] = (acb + j < DIN) ? Abf[(long)(acb + j) * NTOK + atok] : 0.f;
    short8 s;
#pragma unroll
    for (int j = 0; j < 8; ++j) s[j] = f2bf(rf[j]);
    *reinterpret_cast<short8*>(&As[0][atok][acb]) = s;
  } else {
    ra = *reinterpret_cast<const short8*>(&Ab16[(long)arow * K + ak]);
    *reinterpret_cast<short8*>(&As[0][arow][ak]) = ra;
  }
  rb0 = bv0 ? *reinterpret_cast<const short8*>(&Bb[(long)brow * K + bk]) : z8;
  rb1 = bv1 ? *reinterpret_cast<const short8*>(&Bb[(long)(brow + 64) * K + bk])
            : z8;
  *reinterpret_cast<short8*>(&Bs[0][brow][bk]) = rb0;
  *reinterpret_cast<short8*>(&Bs[0][brow + 64][bk]) = rb1;
  __syncthreads();

  floatx4 acc[2][4];
#pragma unroll
  for (int m = 0; m < 2; ++m)
#pragma unroll
    for (int n = 0; n < 4; ++n) acc[m][n] = (floatx4){0.f, 0.f, 0.f, 0.f};

  int NT = K >> 5;
  for (int t = 0; t < NT; ++t) {
    int cur = t & 1;
    if (t + 1 < NT) {
      int ko = (t + 1) << 5;
      if (AFP32) {
#pragma unroll
        for (int j = 0; j < 8; ++j)
          rf[j] = (ko + acb + j < DIN)
                      ? Abf[(long)(ko + acb + j) * NTOK + atok]
                      : 0.f;
      } else {
        ra = *reinterpret_cast<const short8*>(&Ab16[(long)arow * K + ko + ak]);
      }
      rb0 = bv0 ? *reinterpret_cast<const short8*>(&Bb[(long)brow * K + ko + bk])
                : z8;
      rb1 = bv1 ? *reinterpret_cast<const short8*>(
                      &Bb[(long)(brow + 64) * K + ko + bk])
                : z8;
    }
    short8 af[2], bf[4];
#pragma unroll
    for (int m = 0; m < 2; ++m)
      af[m] = *reinterpret_cast<const short8*>(
          &As[cur][wrow + m * 16 + lcol][kg * 8]);
#pragma unroll
    for (int n = 0; n < 4; ++n)
      bf[n] = *reinterpret_cast<const short8*>(
          &Bs[cur][wcol + n * 16 + lcol][kg * 8]);
#pragma unroll
    for (int m = 0; m < 2; ++m)
#pragma unroll
      for (int n = 0; n < 4; ++n)
        acc[m][n] = __builtin_amdgcn_mfma_f32_16x16x32_bf16(af[m], bf[n],
                                                            acc[m][n], 0, 0, 0);
    if (t + 1 < NT) {
      int nxt = cur ^ 1;
      if (AFP32) {
        short8 s;
#pragma unroll
        for (int j = 0; j < 8; ++j) s[j] = f2bf(rf[j]);
        *reinterpret_cast<short8*>(&As[nxt][atok][acb]) = s;
      } else {
        *reinterpret_cast<short8*>(&As[nxt][arow][ak]) = ra;
      }
      *reinterpret_cast<short8*>(&Bs[nxt][brow][bk]) = rb0;
      *reinterpret_cast<short8*>(&Bs[nxt][brow + 64][bk]) = rb1;
    }
    __syncthreads();
  }

  if (OUTMODE == 4) {
    int bb = row0 >> 10;
    int tb0 = (row0 & 1023) + wrow;
    float sqp[2][4] = {};
#pragma unroll
    for (int n = 0; n < 4; ++n) {
      int c = col0 + wcol + n * 16 + lcol;
      if (c < N) {
        float bv = bias[c];
#pragma unroll
        for (int m = 0; m < 2; ++m) {
          int tb = tb0 + m * 16 + kg * 4;
          long addr = ((long)bb * DIN + c) * 1024 + tb;
          float4 qv = *reinterpret_cast<const float4*>(&qfp[addr]);
          float4 ov;
          float v0 = acc[m][n][0] + bv;
          float v1 = acc[m][n][1] + bv;
          float v2 = acc[m][n][2] + bv;
          float v3 = acc[m][n][3] + bv;
          ov.x = v0;
          ov.y = v1;
          ov.z = v2;
          ov.w = v3;
          float d0 = v0 - qv.x, d1 = v1 - qv.y, d2 = v2 - qv.z, d3 = v3 - qv.w;
          sqp[m][0] = fmaf(d0, d0, sqp[m][0]);
          sqp[m][1] = fmaf(d1, d1, sqp[m][1]);
          sqp[m][2] = fmaf(d2, d2, sqp[m][2]);
          sqp[m][3] = fmaf(d3, d3, sqp[m][3]);
          *reinterpret_cast<float4*>(&Cf[addr]) = ov;
        }
      }
    }
#pragma unroll
    for (int m = 0; m < 2; ++m)
#pragma unroll
      for (int q = 0; q < 4; ++q) {
        float s = sqp[m][q];
        s += __shfl_xor(s, 1);
        s += __shfl_xor(s, 2);
        s += __shfl_xor(s, 4);
        s += __shfl_xor(s, 8);
        if (lcol == 0) part_s[wrow + m * 16 + kg * 4 + q][w & 1] = s;
      }
    __syncthreads();
    if (tid < 64)
      ppart[(long)cx * 16384 + row0 + tid] = part_s[tid][0] + part_s[tid][1];
    return;
  }

#pragma unroll
  for (int n = 0; n < 4; ++n) {
    int c = col0 + wcol + n * 16 + lcol;
    if (c >= N) continue;
    float bv = bias[c];
#pragma unroll
    for (int m = 0; m < 2; ++m) {
      int rbase = row0 + wrow + m * 16 + kg * 4;
      if (OUTMODE == 1) {
#pragma unroll
        for (int q = 0; q < 4; ++q)
          Cs[(long)(rbase + q) * N + c] = f2bf(fmaxf(acc[m][n][q] + bv, 0.f));
      } else if (OUTMODE == 3) {
#pragma unroll
        for (int q = 0; q < 4; ++q) {
          float val = acc[m][n][q] + bv;
          Cs[(long)(rbase + q) * N + c] = f2bf(val);
          q16p[(long)(rbase + q) * N + c] =
              f2bf((val + pos[((rbase + q) & 1023) * 256 + c]) * QSCALE);
        }
      }
    }
  }
}

// ---------------------------------------------------------------------------
// MFMA GEMM + fused residual(bf16) + LayerNorm epilogue.
// A bf16 [M][K] @ Wt bf16 [256][K] + bias + res16(bf16) -> LN -> x16out
// (in-place-safe vs res16).  [EQ] also q16out.  Tile 32x256, 4 waves.
// ---------------------------------------------------------------------------
template <bool EQ>
__global__ __launch_bounds__(256) void gemm_ln_kernel(
    const short* __restrict__ A, const short* __restrict__ Wt,
    const float* __restrict__ bias, const short* __restrict__ res16,
    const float* __restrict__ g, const float* __restrict__ bta,
    short* __restrict__ x16out, const float* __restrict__ pos,
    short* __restrict__ q16out, int K) {
  __shared__ short As[2][32][40];
  __shared__ short Bs[2][256][40];
  __shared__ float st_s[32][4];
  __shared__ float st_s2[32][4];
  int tid = threadIdx.x;
  int row0 = blockIdx.x * 32;
  int w = tid >> 6, lane = tid & 63, lcol = lane & 15, kg = lane >> 4;
  int arow = tid >> 2, ak = (tid & 3) * 8;  // tid<128 stages A
  int brow = tid >> 2, bk = (tid & 3) * 8;  // rows brow + i*64
  const short* Ab = A + (long)row0 * K;

  short8 ra, rb[4];
  if (tid < 128) ra = *reinterpret_cast<const short8*>(&Ab[(long)arow * K + ak]);
#pragma unroll
  for (int i = 0; i < 4; ++i)
    rb[i] = *reinterpret_cast<const short8*>(&Wt[(long)(brow + i * 64) * K + bk]);
  if (tid < 128) *reinterpret_cast<short8*>(&As[0][arow][ak]) = ra;
#pragma unroll
  for (int i = 0; i < 4; ++i)
    *reinterpret_cast<short8*>(&Bs[0][brow + i * 64][bk]) = rb[i];
  __syncthreads();

  floatx4 acc[2][4];
#pragma unroll
  for (int m = 0; m < 2; ++m)
#pragma unroll
    for (int n = 0; n < 4; ++n) acc[m][n] = (floatx4){0.f, 0.f, 0.f, 0.f};

  int NT = K >> 5;
  for (int t = 0; t < NT; ++t) {
    int cur = t & 1;
    if (t + 1 < NT) {
      int ko = (t + 1) << 5;
      if (tid < 128)
        ra = *reinterpret_cast<const short8*>(&Ab[(long)arow * K + ko + ak]);
#pragma unroll
      for (int i = 0; i < 4; ++i)
        rb[i] = *reinterpret_cast<const short8*>(
            &Wt[(long)(brow + i * 64) * K + ko + bk]);
    }
    short8 af[2], bf[4];
#pragma unroll
    for (int m = 0; m < 2; ++m)
      af[m] =
          *reinterpret_cast<const short8*>(&As[cur][m * 16 + lcol][kg * 8]);
#pragma unroll
    for (int n = 0; n < 4; ++n)
      bf[n] = *reinterpret_cast<const short8*>(
          &Bs[cur][w * 64 + n * 16 + lcol][kg * 8]);
#pragma unroll
    for (int m = 0; m < 2; ++m)
#pragma unroll
      for (int n = 0; n < 4; ++n)
        acc[m][n] = __builtin_amdgcn_mfma_f32_16x16x32_bf16(af[m], bf[n],
                                                            acc[m][n], 0, 0, 0);
    if (t + 1 < NT) {
      int nxt = cur ^ 1;
      if (tid < 128) *reinterpret_cast<short8*>(&As[nxt][arow][ak]) = ra;
#pragma unroll
      for (int i = 0; i < 4; ++i)
        *reinterpret_cast<short8*>(&Bs[nxt][brow + i * 64][bk]) = rb[i];
    }
    __syncthreads();
  }

  float val[2][4][4];
#pragma unroll
  for (int n = 0; n < 4; ++n) {
    int c = w * 64 + n * 16 + lcol;
    float bv = bias[c];
#pragma unroll
    for (int m = 0; m < 2; ++m) {
      int rbase = row0 + m * 16 + kg * 4;
#pragma unroll
      for (int q = 0; q < 4; ++q)
        val[m][n][q] =
            acc[m][n][q] + bv + bf2f(res16[(long)(rbase + q) * 256 + c]);
    }
  }
  float s[2][4], s2[2][4];
#pragma unroll
  for (int m = 0; m < 2; ++m)
#pragma unroll
    for (int q = 0; q < 4; ++q) {
      float ss = 0.f, ss2 = 0.f;
#pragma unroll
      for (int n = 0; n < 4; ++n) {
        float v = val[m][n][q];
        ss += v;
        ss2 = fmaf(v, v, ss2);
      }
      ss += __shfl_xor(ss, 1);
      ss2 += __shfl_xor(ss2, 1);
      ss += __shfl_xor(ss, 2);
      ss2 += __shfl_xor(ss2, 2);
      ss += __shfl_xor(ss, 4);
      ss2 += __shfl_xor(ss2, 4);
      ss += __shfl_xor(ss, 8);
      ss2 += __shfl_xor(ss2, 8);
      s[m][q] = ss;
      s2[m][q] = ss2;
    }
  if (lcol == 0) {
#pragma unroll
    for (int m = 0; m < 2; ++m)
#pragma unroll
      for (int q = 0; q < 4; ++q) {
        st_s[m * 16 + kg * 4 + q][w] = s[m][q];
        st_s2[m * 16 + kg * 4 + q][w] = s2[m][q];
      }
  }
  __syncthreads();
#pragma unroll
  for (int m = 0; m < 2; ++m)
#pragma unroll
    for (int q = 0; q < 4; ++q) {
      int row = m * 16 + kg * 4 + q;
      float4 a4 = *reinterpret_cast<const float4*>(&st_s[row][0]);
      float4 b4 = *reinterpret_cast<const float4*>(&st_s2[row][0]);
      float S = (a4.x + a4.y) + (a4.z + a4.w);
      float S2 = (b4.x + b4.y) + (b4.z + b4.w);
      float mean = S * (1.f / 256.f);
      float var = S2 * (1.f / 256.f) - mean * mean;
      float inv = rsqrtf(var + LN_EPS);
#pragma unroll
      for (int n = 0; n < 4; ++n) {
        int c = w * 64 + n * 16 + lcol;
        float o = (val[m][n][q] - mean) * inv * g[c] + bta[c];
        long addr = (long)(row0 + row) * 256 + c;
        x16out[addr] = f2bf(o);
        if (EQ)
          q16out[addr] =
              f2bf((o + pos[((row0 + row) & 1023) * 256 + c]) * QSCALE);
      }
    }
}

// ---------------------------------------------------------------------------
// MFMA windowed attention. One block per (b,k,r) (grid 2048, XCD-swizzled).
// Q staged from global q16 (pos+scale pre-folded) via pure bf16 copy; Q/P
// alias one LDS buffer.  S = Q@K'^T (ktp direct); cross-wave softmax; P in
// LDS; O = P@V (ktv = V^T direct).  O bf16.
// ---------------------------------------------------------------------------
__global__ __launch_bounds__(256) void attn_kernel(
    const short* __restrict__ q16, const short* __restrict__ ktp,
    const short* __restrict__ ktv, short* __restrict__ o) {
  __shared__ short QP_s[32][264];
  __shared__ float st_mx[32][4];
  __shared__ float st_sm[32][4];
  int h = blockIdx.x;
  int xcd = h & 7, jj = h >> 3;
  int sidx = xcd * 8 + (jj >> 5);
  int r = jj & 31;
  int b = sidx & 15, k = sidx >> 4;
  int tid = threadIdx.x;
  int w = tid >> 6, lane = tid & 63, lcol = lane & 15, kg = lane >> 4;

  int r0 = max(r - 3, 0), r1 = min(r + 3, 31);
  int nkr = r1 - r0 + 1, nm = nkr * 32;
  const short* qb = q16 + ((long)b * NTOK + r * 32) * HID;
  const short* ktpb = ktp + ((long)(k * BATCH + b)) * NTOK * HID;
  const short* ktvb = ktv + ((long)(k * BATCH + b)) * NTOK * HID;

#pragma unroll
  for (int p = 0; p < 4; ++p) {
    int chunk = p * 256 + tid;
    int row = chunk >> 5, c8 = (chunk & 31) * 8;
    short8 v = *reinterpret_cast<const short8*>(&qb[(long)row * HID + c8]);
    *reinterpret_cast<short8*>(&QP_s[row][c8]) = v;
  }
  __syncthreads();

  floatx4 acc[2][4];
#pragma unroll
  for (int m = 0; m < 2; ++m)
#pragma unroll
    for (int n = 0; n < 4; ++n) acc[m][n] = (floatx4){0.f, 0.f, 0.f, 0.f};

  int tokn[4];
#pragma unroll
  for (int n = 0; n < 4; ++n) {
    int nf = w * 4 + n;
    int krow = min(r0 + (nf >> 1), 31);
    tokn[n] = krow * 32 + ((nf & 1) << 4) + lcol;
  }
#pragma unroll
  for (int s = 0; s < 8; ++s) {
    short8 af0 = *reinterpret_cast<const short8*>(&QP_s[lcol][s * 32 + kg * 8]);
    short8 af1 =
        *reinterpret_cast<const short8*>(&QP_s[16 + lcol][s * 32 + kg * 8]);
#pragma unroll
    for (int n = 0; n < 4; ++n) {
      short8 bfr = *reinterpret_cast<const short8*>(
          &ktpb[(long)tokn[n] * HID + s * 32 + kg * 8]);
      acc[0][n] =
          __builtin_amdgcn_mfma_f32_16x16x32_bf16(af0, bfr, acc[0][n], 0, 0, 0);
      acc[1][n] =
          __builtin_amdgcn_mfma_f32_16x16x32_bf16(af1, bfr, acc[1][n], 0, 0, 0);
    }
  }

  const float NEG = -3.0e38f;
  float mx[2][4];
#pragma unroll
  for (int m = 0; m < 2; ++m)
#pragma unroll
    for (int q = 0; q < 4; ++q) {
      int rr = m * 16 + kg * 4 + q;
      float vmax = NEG;
#pragma unroll
      for (int n = 0; n < 4; ++n) {
        int col = (w * 4 + n) * 16 + lcol;
        int ck = col & 31;
        bool ok = (col < nm) && (ck - rr <= 3) && (rr - ck <= 3);
        float v = ok ? acc[m][n][q] : NEG;
        acc[m][n][q] = v;
        vmax = fmaxf(vmax, v);
      }
      vmax = fmaxf(vmax, __shfl_xor(vmax, 1));
      vmax = fmaxf(vmax, __shfl_xor(vmax, 2));
      vmax = fmaxf(vmax, __shfl_xor(vmax, 4));
      vmax = fmaxf(vmax, __shfl_xor(vmax, 8));
      mx[m][q] = vmax;
    }
  if (lcol == 0) {
#pragma unroll
    for (int m = 0; m < 2; ++m)
#pragma unroll
      for (int q = 0; q < 4; ++q) st_mx[m * 16 + kg * 4 + q][w] = mx[m][q];
  }
  __syncthreads();
  float sm[2][4];
#pragma unroll
  for (int m = 0; m < 2; ++m)
#pragma unroll
    for (int q = 0; q < 4; ++q) {
      int rr = m * 16 + kg * 4 + q;
      float4 v4 = *reinterpret_cast<const float4*>(&st_mx[rr][0]);
      float g = fmaxf(fmaxf(v4.x, v4.y), fmaxf(v4.z, v4.w));
      float ss = 0.f;
#pragma unroll
      for (int n = 0; n < 4; ++n) {
        float v = acc[m][n][q];
        float pv = (v > -1.0e30f) ? exp2f((v - g) * 1.4426950408889634f) : 0.f;
        acc[m][n][q] = pv;
        ss += pv;
      }
      ss += __shfl_xor(ss, 1);
      ss += __shfl_xor(ss, 2);
      ss += __shfl_xor(ss, 4);
      ss += __shfl_xor(ss, 8);
      sm[m][q] = ss;
    }
  if (lcol == 0) {
#pragma unroll
    for (int m = 0; m < 2; ++m)
#pragma unroll
      for (int q = 0; q < 4; ++q) st_sm[m * 16 + kg * 4 + q][w] = sm[m][q];
  }
  __syncthreads();
#pragma unroll
  for (int m = 0; m < 2; ++m)
#pragma unroll
    for (int q = 0; q < 4; ++q) {
      int rr = m * 16 + kg * 4 + q;
      float4 v4 = *reinterpret_cast<const float4*>(&st_sm[rr][0]);
      float rinv = 1.0f / (v4.x + v4.y + v4.z + v4.w);
#pragma unroll
      for (int n = 0; n < 4; ++n) {
        QP_s[rr][(w * 4 + n) * 16 + lcol] = f2bf(acc[m][n][q] * rinv);
      }
    }
  __syncthreads();

  floatx4 oacc[2][4];
#pragma unroll
  for (int m = 0; m < 2; ++m)
#pragma unroll
    for (int n = 0; n < 4; ++n) oacc[m][n] = (floatx4){0.f, 0.f, 0.f, 0.f};

  for (int kb = 0; kb < nkr; ++kb) {
    short8 ap0 = *reinterpret_cast<const short8*>(&QP_s[lcol][kb * 32 + kg * 8]);
    short8 ap1 =
        *reinterpret_cast<const short8*>(&QP_s[16 + lcol][kb * 32 + kg * 8]);
    int tokb = (r0 + kb) * 32;
#pragma unroll
    for (int n = 0; n < 4; ++n) {
      int ch = w * 64 + n * 16 + lcol;
      short8 bv = *reinterpret_cast<const short8*>(
          &ktvb[(long)ch * NTOK + tokb + kg * 8]);
      oacc[0][n] =
          __builtin_amdgcn_mfma_f32_16x16x32_bf16(ap0, bv, oacc[0][n], 0, 0, 0);
      oacc[1][n] =
          __builtin_amdgcn_mfma_f32_16x16x32_bf16(ap1, bv, oacc[1][n], 0, 0, 0);
    }
  }
#pragma unroll
  for (int m = 0; m < 2; ++m)
#pragma unroll
    for (int n = 0; n < 4; ++n) {
      int ch = w * 64 + n * 16 + lcol;
#pragma unroll
      for (int q = 0; q < 4; ++q) {
        int rr = m * 16 + kg * 4 + q;
        o[((long)b * NTOK + r * 32 + rr) * (KMEM * HID) + k * HID + ch] =
            f2bf(oacc[m][n][q]);
      }
    }
}

// ---------------------------------------------------------------------------
// sum the 3 pred partials -> pred_sq, and global min/max of sqrt(pred_sq)
// ---------------------------------------------------------------------------
__global__ __launch_bounds__(256) void minmax_kernel(
    const float* __restrict__ ppart, float* __restrict__ pred_sq,
    float* __restrict__ mnmx) {
  int tid = threadIdx.x;
  float mn = INFINITY, mx = -INFINITY;
  for (int i = tid; i < BATCH * NTOK; i += 256) {
    float v = ppart[i] + ppart[16384 + i] + ppart[32768 + i];
    pred_sq[i] = v;
    float sv = sqrtf(v);
    mn = fminf(mn, sv);
    mx = fmaxf(mx, sv);
  }
#pragma unroll
  for (int off = 32; off > 0; off >>= 1) {
    mn = fminf(mn, __shfl_xor(mn, off));
    mx = fmaxf(mx, __shfl_xor(mx, off));
  }
  __shared__ float smn[4], smx[4];
  int wave = tid >> 6, lane = tid & 63;
  if (lane == 0) {
    smn[wave] = mn;
    smx[wave] = mx;
  }
  __syncthreads();
  if (tid == 0) {
    mn = fminf(fminf(smn[0], smn[1]), fminf(smn[2], smn[3]));
    mx = fmaxf(fmaxf(smx[0], smx[1]), fmaxf(smx[2], smx[3]));
    mnmx[0] = mn;
    mnmx[1] = mx;
  }
}

__global__ __launch_bounds__(256) void resize_kernel(
    const float* __restrict__ pred_sq, const float* __restrict__ mnmx,
    float* __restrict__ out) {
  long idx = (long)blockIdx.x * 256 + threadIdx.x;
  if (idx >= (long)BATCH * 256 * 256) return;
  int b = (int)(idx >> 16);
  int oy = (int)((idx >> 8) & 255), ox = (int)(idx & 255);
  float mn = mnmx[0], mx = mnmx[1];
  float inv = 1.0f / (mx - mn);
  float ys = oy * (31.0f / 255.0f);
  int y0 = (int)floorf(ys);
  int y1 = min(y0 + 1, 31);
  float fy = ys - (float)y0;
  float xs = ox * (31.0f / 255.0f);
  int x0 = (int)floorf(xs);
  int x1 = min(x0 + 1, 31);
  float fx = xs - (float)x0;
  const float* p = pred_sq + b * NTOK;
  float v00 = sqrtf(p[y0 * 32 + x0]), v01 = sqrtf(p[y0 * 32 + x1]);
  float v10 = sqrtf(p[y1 * 32 + x0]), v11 = sqrtf(p[y1 * 32 + x1]);
  float cA = v00 * (1.f - fy) + v10 * fy;
  float cB = v01 * (1.f - fy) + v11 * fy;
  float v = cA * (1.f - fx) + cB * fx;
  out[idx] = (v - mn) * inv;
}

// ---------------------------------------------------------------------------
extern "C" void kernel_launch(void* const* d_in, const int* in_sizes, int n_in,
                              void* d_out, int out_size, void* d_ws,
                              size_t ws_size, hipStream_t stream) {
  const float* qf = (const float*)d_in[0];
  const float* mf = (const float*)d_in[1];
  const float* qW = (const float*)d_in[2];
  const float* qb = (const float*)d_in[3];
  const float* kvW = (const float*)d_in[4];
  const float* kvb = (const float*)d_in[5];
  const float* row_e = (const float*)d_in[6];
  const float* col_e = (const float*)d_in[7];
  const float* aggW = (const float*)d_in[8];
  const float* aggb = (const float*)d_in[9];
  const float* n1g = (const float*)d_in[10];
  const float* n1b = (const float*)d_in[11];
  const float* l1W = (const float*)d_in[12];
  const float* l1b = (const float*)d_in[13];
  const float* l2W = (const float*)d_in[14];
  const float* l2b = (const float*)d_in[15];
  const float* n2g = (const float*)d_in[16];
  const float* n2b = (const float*)d_in[17];
  const float* outW = (const float*)d_in[18];
  const float* outb = (const float*)d_in[19];

  float* out = (float*)d_out;
  float* recon = out;                            // 16*272*1024
  float* pred = out + (long)BATCH * DIN * NTOK;  // 16*256*256

  // workspace layout (residual carried in bf16 x16)
  float* ws = (float*)d_ws;
  float* pos = ws;                              // 262144 f   (1MB)
  short* x16 = (short*)(pos + 262144);          // 4194304 s  (8MB)
  short* q16 = x16 + 4194304;                   // 4194304 s  (8MB)
  short* ktp = q16 + 4194304;                   // 16777216 s (32MB)
  short* ktv = ktp + 16777216;                  // 16777216 s (32MB)
  short* buf16 = ktv + 16777216;                // 16777216 s (32MB)
  short* wt = buf16 + 16777216;
  short* wt_agg0 = wt;                  // [256][1024]
  short* wt_agg1 = wt_agg0 + 262144;    // [256][1024]
  short* wt_l1_0 = wt_agg1 + 262144;    // [1024][256]
  short* wt_l1_1 = wt_l1_0 + 262144;    // [1024][256]
  short* wt_l2_0 = wt_l1_1 + 262144;    // [256][1024]
  short* wt_l2_1 = wt_l2_0 + 262144;    // [256][1024]
  short* wt_out = wt_l2_1 + 262144;     // [272][256]
  short* wt_q = wt_out + 69632;         // [256][288]
  short* wt_kv = wt_q + 73728;          // [256][288]
  float* pred_part = (float*)(wt_kv + 73728);   // 49152 f (3 x 16384)
  float* pred_sq = pred_part + 49152;           // 16384 f
  float* mnmx = pred_sq + 16384;                // 2 f

  pos_kernel<<<NTOK, 256, 0, stream>>>(row_e, col_e, pos);

  // all weight transposes in one dispatch
  {
    WtJobs jobs;
    jobs.j[0] = {aggW, wt_agg0, 1024, 1024, 256, 8, 0};
    jobs.j[1] = {aggW + 262144, wt_agg1, 1024, 1024, 256, 8, 256};
    jobs.j[2] = {l1W, wt_l1_0, 256, 256, 1024, 32, 512};
    jobs.j[3] = {l1W + 262144, wt_l1_1, 256, 256, 1024, 32, 768};
    jobs.j[4] = {l2W, wt_l2_0, 1024, 1024, 256, 8, 1024};
    jobs.j[5] = {l2W + 262144, wt_l2_1, 1024, 1024, 256, 8, 1280};
    jobs.j[6] = {outW, wt_out, 256, 256, 272, 9, 1536};
    jobs.j[7] = {qW, wt_q, 272, 288, 256, 8, 1608};
    jobs.j[8] = {kvW, wt_kv, 272, 288, 256, 8, 1680};
    wt_cvt_all_kernel<<<1752, 256, 0, stream>>>(jobs);
  }

  // q projection: x16 (bf16 residual) + q16 = bf16((val+pos)*scale)
  gemm2_kernel<3, true><<<512, 256, 0, stream>>>(
      qf, wt_q, qb, nullptr, x16, BATCH * NTOK, HID, DINP, 2, q16, pos,
      nullptr, nullptr);
  // kv projection: two-pass 64x128 tile (30 KB LDS, high occupancy)
  kvproj_kernel<<<2048, 256, 0, stream>>>(mf, wt_kv, kvb, ktp, ktv, pos);

  for (int l = 0; l < 2; l++) {
    attn_kernel<<<2048, 256, 0, stream>>>(q16, ktp, ktv, buf16);
    // agg + LN1 fused (res = x16, in-place): -> x16
    gemm_ln_kernel<false><<<512, 256, 0, stream>>>(
        buf16, l ? wt_agg1 : wt_agg0, aggb + l * 256, x16, n1g + l * 256,
        n1b + l * 256, x16, nullptr, nullptr, KMEM * HID);
    // ff1: x16 @ wt_l1 -> relu bf16 buf16
    gemm2_kernel<1, false><<<2048, 256, 0, stream>>>(
        x16, l ? wt_l1_1 : wt_l1_0, l1b + l * 1024, nullptr, buf16,
        BATCH * NTOK, DFF, HID, 8, nullptr, nullptr, nullptr, nullptr);
    // ff2 + LN2 fused: l=0 also emits q16 for the next attn
    if (l == 0) {
      gemm_ln_kernel<true><<<512, 256, 0, stream>>>(
          buf16, wt_l2_0, l2b, x16, n2g, n2b, x16, pos, q16, DFF);
    } else {
      gemm_ln_kernel<false><<<512, 256, 0, stream>>>(
          buf16, wt_l2_1, l2b + 256, x16, n2g + 256, n2b + 256, x16, nullptr,
          nullptr, DFF);
    }
  }

  // out projection fused: x16 @ wt_out -> recon (transposed) + pred partials
  gemm2_kernel<4, false><<<768, 256, 0, stream>>>(
      x16, wt_out, outb, recon, nullptr, BATCH * NTOK, DIN, HID, 3, nullptr,
      nullptr, qf, pred_part);
  minmax_kernel<<<1, 256, 0, stream>>>(pred_part, pred_sq, mnmx);
  resize_kernel<<<(BATCH * 256 * 256) / 256, 256, 0, stream>>>(pred_sq, mnmx,
                                                               pred);
}